// Round 1
// baseline (3441.121 us; speedup 1.0000x reference)
//
#include <hip/hip_runtime.h>
#include <hip/hip_bf16.h>
#include <math.h>

#define M1 2048
#define M2 2048
#define DIM 128
#define NDIAG (M1 + M2 - 1)   // 4095 diagonals of C (d = a+b, 0..4094)

// Compact diagonal-major layout of the cost matrix:
// diag d holds cells (a, b=d-a) for a in [max(0,d-2047), min(2047,d)],
// stored contiguously; total = 2048^2 floats.
__device__ __host__ __forceinline__ int diag_off(int d) {
    if (d <= 2048) return d * (d + 1) / 2;
    int u = d - 2048;
    return 2098176 + u * 2047 - u * (u - 1) / 2;  // 2098176 = 2048*2049/2
}

// ---------------- row norms ----------------
__global__ __launch_bounds__(64) void norm_kernel(const float* __restrict__ X1,
                                                  const float* __restrict__ X2,
                                                  float* __restrict__ n1,
                                                  float* __restrict__ n2) {
    int b = blockIdx.x;                 // 0..4095: first 2048 -> X1 rows, rest -> X2 rows
    const float* src = (b < M1) ? X1 : X2;
    int row = b & (M1 - 1);
    int t = threadIdx.x;
    float a = src[row * DIM + t];
    float c = src[row * DIM + t + 64];
    float s = a * a + c * c;
    #pragma unroll
    for (int o = 32; o > 0; o >>= 1) s += __shfl_down(s, o);
    if (t == 0) ((b < M1) ? n1 : n2)[row] = s;
}

// ---------------- cost matrix (diag-major output) ----------------
__global__ __launch_bounds__(256) void cost_kernel(const float* __restrict__ X1,
                                                   const float* __restrict__ X2,
                                                   const float* __restrict__ n1,
                                                   const float* __restrict__ n2,
                                                   float* __restrict__ Cd) {
    __shared__ float As[32][129];   // +1 pad: conflict-free scalar reads
    __shared__ float Bs[32][129];
    const int tx = threadIdx.x & 15;
    const int ty = threadIdx.x >> 4;
    const int rowBase = blockIdx.y * 32;
    const int colBase = blockIdx.x * 32;

    // stage 32x128 tiles of X1 and X2 (float4, coalesced)
    #pragma unroll
    for (int r = 0; r < 4; ++r) {
        int idx = threadIdx.x + 256 * r;   // float4 slot 0..1023
        int row = idx >> 5;
        int c4 = (idx & 31) * 4;
        float4 va = *(const float4*)&X1[(rowBase + row) * DIM + c4];
        As[row][c4 + 0] = va.x; As[row][c4 + 1] = va.y;
        As[row][c4 + 2] = va.z; As[row][c4 + 3] = va.w;
        float4 vb = *(const float4*)&X2[(colBase + row) * DIM + c4];
        Bs[row][c4 + 0] = vb.x; Bs[row][c4 + 1] = vb.y;
        Bs[row][c4 + 2] = vb.z; Bs[row][c4 + 3] = vb.w;
    }
    __syncthreads();

    float acc[2][2] = {{0.f, 0.f}, {0.f, 0.f}};
    const int a0 = ty * 2, b0 = tx * 2;
    #pragma unroll 4
    for (int kk = 0; kk < DIM; ++kk) {
        float av0 = As[a0][kk], av1 = As[a0 + 1][kk];
        float bv0 = Bs[b0][kk], bv1 = Bs[b0 + 1][kk];
        acc[0][0] += av0 * bv0;
        acc[0][1] += av0 * bv1;
        acc[1][0] += av1 * bv0;
        acc[1][1] += av1 * bv1;
    }

    #pragma unroll
    for (int u = 0; u < 2; ++u)
        #pragma unroll
        for (int v = 0; v < 2; ++v) {
            int a = rowBase + a0 + u;
            int b = colBase + b0 + v;
            int d = a + b;
            int amin = (d > 2047) ? (d - 2047) : 0;
            Cd[diag_off(d) + (a - amin)] = n1[a] + n2[b] - 2.0f * acc[u][v];
        }
}

// ---------------- DP wavefront (single workgroup) ----------------
__global__ __launch_bounds__(1024) void dp_kernel(const float* __restrict__ Cd,
                                                  float* __restrict__ out) {
    __shared__ float R[3][M1 + 1];       // diag buffers indexed by row i in [0,2048]
    const float INF = __builtin_inff();
    const int t = threadIdx.x;

    for (int i = t; i <= M1; i += 1024) {
        R[0][i] = (i == 0) ? 0.0f : INF;   // diag k=0: only R[0][0]=0
        R[1][i] = INF;                      // diag k=1: all borders
    }
    __syncthreads();

    for (int k = 2; k <= M1 + M2; ++k) {
        float* cur = R[k % 3];
        const float* p1 = R[(k - 1) % 3];
        const float* p2 = R[(k - 2) % 3];
        const int d = k - 2;                       // cost-diagonal index
        const int off = diag_off(d);
        const int amin = (d > 2047) ? (d - 2047) : 0;

        #pragma unroll
        for (int rep = 0; rep < 2; ++rep) {
            int i = t + 1 + rep * 1024;
            if (i <= M1) {
                int j = k - i;
                float r;
                if (j >= 1 && j <= M2) {
                    float x = p1[i - 1];   // R[i-1][j]
                    float y = p1[i];       // R[i][j-1]
                    float z = p2[i - 1];   // R[i-1][j-1]
                    float mn = fminf(x, fminf(y, z));
                    float sm;
                    if (mn > 3.0e38f) {
                        sm = INF;          // all-inf guard
                    } else {
                        sm = mn - __logf(__expf(mn - x) + __expf(mn - y) + __expf(mn - z));
                    }
                    float c = Cd[off + (i - 1) - amin];
                    r = c + sm;
                } else {
                    r = INF;
                }
                cur[i] = r;
            }
        }
        if (t == 0) cur[0] = INF;
        __syncthreads();
    }

    if (t == 0) out[0] = R[(M1 + M2) % 3][M1];
}

extern "C" void kernel_launch(void* const* d_in, const int* in_sizes, int n_in,
                              void* d_out, int out_size, void* d_ws, size_t ws_size,
                              hipStream_t stream) {
    const float* x1 = (const float*)d_in[0];   // y
    const float* x2 = (const float*)d_in[1];   // x2
    float* out = (float*)d_out;

    float* Cd = (float*)d_ws;                  // 2048^2 floats = 16.78 MB
    float* n1 = Cd + M1 * M2;
    float* n2 = n1 + M1;

    norm_kernel<<<4096, 64, 0, stream>>>(x1, x2, n1, n2);
    cost_kernel<<<dim3(M2 / 32, M1 / 32), 256, 0, stream>>>(x1, x2, n1, n2, Cd);
    dp_kernel<<<1, 1024, 0, stream>>>(Cd, out);
}

// Round 3
// 1359.682 us; speedup vs baseline: 2.5308x; 2.5308x over previous
//
#include <hip/hip_runtime.h>
#include <hip/hip_bf16.h>

#define M1 2048
#define M2 2048
#define DIM 128
#define NB 32          // row bands
#define BH 64          // band height = wave size
#define JC 64          // steps per chunk
#define NCHUNK 33      // 2112 band-steps / 64
#define TMAX 95        // 2*31 + 33 time-steps
#define INFF __builtin_inff()

// Fast transcendentals via raw VOP1 (avoids glibc __exp2f/__log2f macro clash).
__device__ __forceinline__ float ex2(float x) {
    float r; asm("v_exp_f32 %0, %1" : "=v"(r) : "v"(x)); return r;
}
__device__ __forceinline__ float lg2(float x) {
    float r; asm("v_log_f32 %0, %1" : "=v"(r) : "v"(x)); return r;
}

// Compact diagonal-major layout of the cost matrix:
// diag d holds cells (a, b=d-a) for a in [max(0,d-2047), min(2047,d)].
__device__ __host__ __forceinline__ int diag_off(int d) {
    if (d <= 2048) return d * (d + 1) / 2;
    int u = d - 2048;
    return 2098176 + u * 2047 - u * (u - 1) / 2;  // 2098176 = 2048*2049/2
}

// ---------------- row norms ----------------
__global__ __launch_bounds__(64) void norm_kernel(const float* __restrict__ X1,
                                                  const float* __restrict__ X2,
                                                  float* __restrict__ n1,
                                                  float* __restrict__ n2) {
    int b = blockIdx.x;
    const float* src = (b < M1) ? X1 : X2;
    int row = b & (M1 - 1);
    int t = threadIdx.x;
    float a = src[row * DIM + t];
    float c = src[row * DIM + t + 64];
    float s = a * a + c * c;
    #pragma unroll
    for (int o = 32; o > 0; o >>= 1) s += __shfl_down(s, o);
    if (t == 0) ((b < M1) ? n1 : n2)[row] = s;
}

// ---------------- cost matrix (diag-major output) ----------------
__global__ __launch_bounds__(256) void cost_kernel(const float* __restrict__ X1,
                                                   const float* __restrict__ X2,
                                                   const float* __restrict__ n1,
                                                   const float* __restrict__ n2,
                                                   float* __restrict__ Cd) {
    __shared__ float As[32][129];
    __shared__ float Bs[32][129];
    const int tx = threadIdx.x & 15;
    const int ty = threadIdx.x >> 4;
    const int rowBase = blockIdx.y * 32;
    const int colBase = blockIdx.x * 32;

    #pragma unroll
    for (int r = 0; r < 4; ++r) {
        int idx = threadIdx.x + 256 * r;
        int row = idx >> 5;
        int c4 = (idx & 31) * 4;
        float4 va = *(const float4*)&X1[(rowBase + row) * DIM + c4];
        As[row][c4 + 0] = va.x; As[row][c4 + 1] = va.y;
        As[row][c4 + 2] = va.z; As[row][c4 + 3] = va.w;
        float4 vb = *(const float4*)&X2[(colBase + row) * DIM + c4];
        Bs[row][c4 + 0] = vb.x; Bs[row][c4 + 1] = vb.y;
        Bs[row][c4 + 2] = vb.z; Bs[row][c4 + 3] = vb.w;
    }
    __syncthreads();

    float acc[2][2] = {{0.f, 0.f}, {0.f, 0.f}};
    const int a0 = ty * 2, b0 = tx * 2;
    #pragma unroll 4
    for (int kk = 0; kk < DIM; ++kk) {
        float av0 = As[a0][kk], av1 = As[a0 + 1][kk];
        float bv0 = Bs[b0][kk], bv1 = Bs[b0 + 1][kk];
        acc[0][0] += av0 * bv0;
        acc[0][1] += av0 * bv1;
        acc[1][0] += av1 * bv0;
        acc[1][1] += av1 * bv1;
    }

    #pragma unroll
    for (int u = 0; u < 2; ++u)
        #pragma unroll
        for (int v = 0; v < 2; ++v) {
            int a = rowBase + a0 + u;
            int b = colBase + b0 + v;
            int d = a + b;
            int amin = (d > 2047) ? (d - 2047) : 0;
            Cd[diag_off(d) + (a - amin)] = n1[a] + n2[b] - 2.0f * acc[u][v];
        }
}

// ---------------- DP: wave-pipelined bands, shuffle wavefront ----------------
// Band b = rows i in [1+64b, 64+64b]; lane l owns row i0+l. At band-step s
// (1..2112) lane l computes cell (i, j=s-l). Neighbors:
//   up   R[i-1][j]   = shfl_up(r1, 1)   (lane0: LDS ring of band b-1)
//   diag R[i-1][j-1] = previous step's u (register carry)
//   left R[i][j-1]   = own r1
// Chunk = 64 steps; task (b,c) runs at time t = 2b + c; one barrier per t.
__global__ __launch_bounds__(1024) void dp_kernel(const float* __restrict__ Cd,
                                                  float* __restrict__ out) {
    __shared__ float ring[NB - 1][256];
    const int tid = threadIdx.x;
    const int lane = tid & 63;
    const int w = __builtin_amdgcn_readfirstlane(tid >> 6);
    const bool l0 = (lane == 0);
    const bool l63 = (lane == 63);

    float r1A = INFF, upA = INFF;
    if (l0 && w == 0) upA = 0.0f;       // R[0][0] = 0 feeds cell (1,1)'s diag
    float r1B = INFF, upB = INFF;

    auto runChunk = [&](int b, int c, float& r1, float& uprev,
                        bool isB0, bool isLastBand) {
        const int s0 = JC * c;
        const int abase = BH * b + lane;           // a = i-1 (0-based cost row)
        int d = BH * b + s0;                        // cost-diag index for q=0
        int off = diag_off(d);
        float ca[JC];
        #pragma unroll
        for (int q = 0; q < JC; ++q) {
            int amin = (d > 2047) ? (d - 2047) : 0;
            ca[q] = Cd[off + abase - amin];          // coalesced: lane-stride 1
            off += (d <= 2047) ? (d + 1) : (4095 - d);   // += len(d)
            d += 1;
        }
        const float* rg = ring[isB0 ? 0 : (b - 1)];
        const float K   = 1.4426950408889634f;      // log2(e)
        const float LN2 = 0.6931471805599453f;
        int s = s0 + 1;
        #pragma unroll
        for (int q = 0; q < JC; ++q) {
            float ringv = rg[s & 255];               // same-addr broadcast read
            if (isB0) ringv = INFF;                  // virtual row 0: R[0][j>=1]=inf
            float u = __shfl_up(r1, 1);
            if (l0) u = ringv;                       // R[i0-1][s]
            float dg = uprev;                        // R[i-1][j-1]
            float left = r1;                         // R[i][j-1]
            float mn = fminf(fminf(u, left), dg);
            float mx = fmaxf(fmaxf(u, left), dg);
            float md = __builtin_amdgcn_fmed3f(u, left, dg);
            // softmin = mn - ln(1 + 2^((mn-md)lg e) + 2^((mn-mx)lg e))
            float e1 = ex2((mn - md) * K);
            float e2 = ex2((mn - mx) * K);
            float sm = mn - LN2 * lg2(1.0f + e1 + e2);
            int j = s - lane;
            bool valid = (unsigned)(j - 1) < (unsigned)M2;
            float rn = valid ? ca[q] + sm : INFF;
            if (!isLastBand) {
                if (l63) ring[b][(s - 63) & 255] = rn;  // publish row i0+63
            } else if (l63 && s == 2111) {
                out[0] = rn;                         // R[2048][2048]
            }
            uprev = u;
            r1 = rn;
            s += 1;
        }
    };

    __syncthreads();
    for (int tt = 0; tt < TMAX; ++tt) {
        int cA = tt - 2 * w;                          // band w
        if ((unsigned)cA < (unsigned)NCHUNK) runChunk(w, cA, r1A, upA, w == 0, false);
        int cB = tt - 2 * w - 32;                     // band w+16
        if ((unsigned)cB < (unsigned)NCHUNK) runChunk(w + 16, cB, r1B, upB, false, w == 15);
        __syncthreads();
    }
}

extern "C" void kernel_launch(void* const* d_in, const int* in_sizes, int n_in,
                              void* d_out, int out_size, void* d_ws, size_t ws_size,
                              hipStream_t stream) {
    const float* x1 = (const float*)d_in[0];   // y
    const float* x2 = (const float*)d_in[1];   // x2
    float* out = (float*)d_out;

    float* Cd = (float*)d_ws;                  // 2048^2 floats
    float* n1 = Cd + M1 * M2;
    float* n2 = n1 + M1;

    norm_kernel<<<4096, 64, 0, stream>>>(x1, x2, n1, n2);
    cost_kernel<<<dim3(M2 / 32, M1 / 32), 256, 0, stream>>>(x1, x2, n1, n2, Cd);
    dp_kernel<<<1, 1024, 0, stream>>>(Cd, out);
}

// Round 4
// 924.729 us; speedup vs baseline: 3.7212x; 1.4704x over previous
//
#include <hip/hip_runtime.h>
#include <hip/hip_bf16.h>

#define M1 2048
#define M2 2048
#define DIM 128
#define NB 32          // row bands
#define BH 64          // band height = wave size
#define JC 64          // steps per chunk
#define NCHUNK 33      // 2112 band-steps / 64
#define TMAX 95        // 2*31 + 33 time-steps
#define INFF __builtin_inff()
#define K2f  1.4426950408889634f   // log2(e)
#define LN2f 0.6931471805599453f

// Fast transcendentals via raw VOP1 (avoids glibc __exp2f/__log2f macro clash).
__device__ __forceinline__ float ex2(float x) {
    float r; asm("v_exp_f32 %0, %1" : "=v"(r) : "v"(x)); return r;
}
__device__ __forceinline__ float lg2(float x) {
    float r; asm("v_log_f32 %0, %1" : "=v"(r) : "v"(x)); return r;
}

// Compact diagonal-major layout of the cost matrix:
// diag d holds cells (a, b=d-a) for a in [max(0,d-2047), min(2047,d)].
__device__ __host__ __forceinline__ int diag_off(int d) {
    if (d <= 2048) return d * (d + 1) / 2;
    int u = d - 2048;
    return 2098176 + u * 2047 - u * (u - 1) / 2;  // 2098176 = 2048*2049/2
}

// ---------------- row norms ----------------
__global__ __launch_bounds__(64) void norm_kernel(const float* __restrict__ X1,
                                                  const float* __restrict__ X2,
                                                  float* __restrict__ n1,
                                                  float* __restrict__ n2) {
    int b = blockIdx.x;
    const float* src = (b < M1) ? X1 : X2;
    int row = b & (M1 - 1);
    int t = threadIdx.x;
    float a = src[row * DIM + t];
    float c = src[row * DIM + t + 64];
    float s = a * a + c * c;
    #pragma unroll
    for (int o = 32; o > 0; o >>= 1) s += __shfl_down(s, o);
    if (t == 0) ((b < M1) ? n1 : n2)[row] = s;
}

// ---------------- cost matrix (diag-major output, pre-scaled by log2 e) ----
__global__ __launch_bounds__(256) void cost_kernel(const float* __restrict__ X1,
                                                   const float* __restrict__ X2,
                                                   const float* __restrict__ n1,
                                                   const float* __restrict__ n2,
                                                   float* __restrict__ Cd) {
    __shared__ float As[32][129];
    __shared__ float Bs[32][129];
    const int tx = threadIdx.x & 15;
    const int ty = threadIdx.x >> 4;
    const int rowBase = blockIdx.y * 32;
    const int colBase = blockIdx.x * 32;

    #pragma unroll
    for (int r = 0; r < 4; ++r) {
        int idx = threadIdx.x + 256 * r;
        int row = idx >> 5;
        int c4 = (idx & 31) * 4;
        float4 va = *(const float4*)&X1[(rowBase + row) * DIM + c4];
        As[row][c4 + 0] = va.x; As[row][c4 + 1] = va.y;
        As[row][c4 + 2] = va.z; As[row][c4 + 3] = va.w;
        float4 vb = *(const float4*)&X2[(colBase + row) * DIM + c4];
        Bs[row][c4 + 0] = vb.x; Bs[row][c4 + 1] = vb.y;
        Bs[row][c4 + 2] = vb.z; Bs[row][c4 + 3] = vb.w;
    }
    __syncthreads();

    float acc[2][2] = {{0.f, 0.f}, {0.f, 0.f}};
    const int a0 = ty * 2, b0 = tx * 2;
    #pragma unroll 4
    for (int kk = 0; kk < DIM; ++kk) {
        float av0 = As[a0][kk], av1 = As[a0 + 1][kk];
        float bv0 = Bs[b0][kk], bv1 = Bs[b0 + 1][kk];
        acc[0][0] += av0 * bv0;
        acc[0][1] += av0 * bv1;
        acc[1][0] += av1 * bv0;
        acc[1][1] += av1 * bv1;
    }

    #pragma unroll
    for (int u = 0; u < 2; ++u)
        #pragma unroll
        for (int v = 0; v < 2; ++v) {
            int a = rowBase + a0 + u;
            int b = colBase + b0 + v;
            int d = a + b;
            int amin = (d > 2047) ? (d - 2047) : 0;
            Cd[diag_off(d) + (a - amin)] = K2f * (n1[a] + n2[b] - 2.0f * acc[u][v]);
        }
}

// ---------------- DP: wave-pipelined bands, DPP wavefront ----------------
// Band b = rows i in [1+64b, 64+64b]; lane l owns row i0+l. At band-step s
// lane l computes cell (i, j=s-l). up via v_mov_dpp wave_shr:1 (lane0 takes
// the LDS ring value as the DPP 'old' operand); diag = previous step's up;
// left = own r1. All R values are in base-2 units (C pre-scaled by log2 e).
// Ring entry for column j lives at (j-1) & 255.
__global__ __launch_bounds__(1024) void dp_kernel(const float* __restrict__ Cd,
                                                  float* __restrict__ out) {
    __shared__ float ring[NB][256];     // row NB-1 = permanent +inf source for band 0
    const int tid = threadIdx.x;
    const int lane = tid & 63;
    const int w = __builtin_amdgcn_readfirstlane(tid >> 6);
    const bool l63 = (lane == 63);

    if (tid < 256) ring[NB - 1][tid] = INFF;

    float r1A = INFF, upA = (tid == 0) ? 0.0f : INFF;   // R[0][0]=0 feeds (1,1)
    float r1B = INFF, upB = INFF;
    __syncthreads();

    auto runChunk = [&](int b, int c, float& r1, float& uprev, bool isLast) {
        const int s0 = JC * c;
        const int abase = BH * b + lane;            // a = i-1 (0-based cost row)
        int d = BH * b + s0;                         // cost-diag index for q=0
        // uniform element offset; per-lane index abase rides in the VGPR offset
        const float* pu = Cd + (diag_off(d) - ((d > 2047) ? (d - 2047) : 0));
        const float* rg = ring[(b == 0) ? (NB - 1) : (b - 1)];
        float* wrp = ring[b];

        float buf[3][8], rh[8];

#define DSTEP { int dd = d; \
                pu += (dd <= 2046) ? (dd + 1) : ((dd == 2047) ? 2047 : (4094 - dd)); \
                d = dd + 1; }
#define ISSUE8(B) { _Pragma("unroll") \
                    for (int k = 0; k < 8; ++k) { (B)[k] = pu[abase]; DSTEP } }

        ISSUE8(buf[0])
        ISSUE8(buf[1])
        #pragma unroll
        for (int g = 0; g < 8; ++g) {
            if (g < 6) ISSUE8(buf[(g + 2) % 3])
            const int sbase = s0 + 1 + g * 8;
            const int rb = (sbase - 1) & 255;        // multiple of 8: no wrap in group
            #pragma unroll
            for (int k = 0; k < 8; ++k) {
                float ringv = rg[rb + k];             // broadcast ds_read (off-chain)
                float u = __int_as_float(__builtin_amdgcn_update_dpp(
                              __float_as_int(ringv), __float_as_int(r1),
                              0x138 /*wave_shr:1*/, 0xF, 0xF, false));
                float mn = fminf(fminf(u, r1), uprev);
                float md = __builtin_amdgcn_fmed3f(u, r1, uprev);
                float mx = fmaxf(fmaxf(u, r1), uprev);
                float sm = mn - lg2(1.0f + ex2(mn - md) + ex2(mn - mx));
                float rn = ((unsigned)(sbase + k - 1 - lane) <= 2047u)
                               ? (buf[g % 3][k] + sm) : INFF;
                rh[k] = rn;
                uprev = u;
                r1 = rn;
            }
            if (!isLast) {
                if (l63) {
                    #pragma unroll
                    for (int k = 0; k < 8; ++k)
                        wrp[(sbase + k - 64) & 255] = rh[k];   // col j at (j-1)&255
                }
            } else if (sbase == 2105) {
                if (l63) out[0] = rh[6] * LN2f;      // s = 2111 -> R[2048][2048]
            }
        }
#undef ISSUE8
#undef DSTEP
    };

    for (int tt = 0; tt < TMAX; ++tt) {
        int cA = tt - 2 * w;                          // band w
        if ((unsigned)cA < (unsigned)NCHUNK) runChunk(w, cA, r1A, upA, false);
        int cB = tt - 2 * w - 32;                     // band w+16
        if ((unsigned)cB < (unsigned)NCHUNK) runChunk(w + 16, cB, r1B, upB, w == 15);
        __syncthreads();
    }
}

extern "C" void kernel_launch(void* const* d_in, const int* in_sizes, int n_in,
                              void* d_out, int out_size, void* d_ws, size_t ws_size,
                              hipStream_t stream) {
    const float* x1 = (const float*)d_in[0];   // y
    const float* x2 = (const float*)d_in[1];   // x2
    float* out = (float*)d_out;

    float* Cd = (float*)d_ws;                  // 2048^2 floats
    float* n1 = Cd + M1 * M2;
    float* n2 = n1 + M1;

    norm_kernel<<<4096, 64, 0, stream>>>(x1, x2, n1, n2);
    cost_kernel<<<dim3(M2 / 32, M1 / 32), 256, 0, stream>>>(x1, x2, n1, n2, Cd);
    dp_kernel<<<1, 1024, 0, stream>>>(Cd, out);
}

// Round 5
// 632.004 us; speedup vs baseline: 5.4448x; 1.4632x over previous
//
#include <hip/hip_runtime.h>
#include <hip/hip_bf16.h>

#define M1 2048
#define M2 2048
#define DIM 128
#define NBAND 32       // one 64-row band per workgroup (one wave)
#define JC 64          // steps per chunk
#define NCHUNK 33      // 2112 band-steps / 64
#define SLOTS 2176     // interface slots per band (2112 used + pad for c=32 reads)
#define INFF __builtin_inff()
#define K2f  1.4426950408889634f   // log2(e)
#define LN2f 0.6931471805599453f

// Fast transcendentals via raw VOP1 (avoids glibc __exp2f/__log2f macro clash).
__device__ __forceinline__ float ex2(float x) {
    float r; asm("v_exp_f32 %0, %1" : "=v"(r) : "v"(x)); return r;
}
__device__ __forceinline__ float lg2(float x) {
    float r; asm("v_log_f32 %0, %1" : "=v"(r) : "v"(x)); return r;
}

// Compact diagonal-major layout of the cost matrix:
// diag d holds cells (a, b=d-a) for a in [max(0,d-2047), min(2047,d)].
__device__ __host__ __forceinline__ int diag_off(int d) {
    if (d <= 2048) return d * (d + 1) / 2;
    int u = d - 2048;
    return 2098176 + u * 2047 - u * (u - 1) / 2;  // 2098176 = 2048*2049/2
}

// ---------------- row norms (+ flag init, runs before dp in stream order) ----
__global__ __launch_bounds__(64) void norm_kernel(const float* __restrict__ X1,
                                                  const float* __restrict__ X2,
                                                  float* __restrict__ n1,
                                                  float* __restrict__ n2,
                                                  int* __restrict__ flags) {
    if (blockIdx.x == 0 && threadIdx.x < NBAND) flags[threadIdx.x] = 0;
    int b = blockIdx.x;
    const float* src = (b < M1) ? X1 : X2;
    int row = b & (M1 - 1);
    int t = threadIdx.x;
    float a = src[row * DIM + t];
    float c = src[row * DIM + t + 64];
    float s = a * a + c * c;
    #pragma unroll
    for (int o = 32; o > 0; o >>= 1) s += __shfl_down(s, o);
    if (t == 0) ((b < M1) ? n1 : n2)[row] = s;
}

// ---------------- cost matrix (diag-major output, pre-scaled by log2 e) ----
__global__ __launch_bounds__(256) void cost_kernel(const float* __restrict__ X1,
                                                   const float* __restrict__ X2,
                                                   const float* __restrict__ n1,
                                                   const float* __restrict__ n2,
                                                   float* __restrict__ Cd) {
    __shared__ float As[32][129];
    __shared__ float Bs[32][129];
    const int tx = threadIdx.x & 15;
    const int ty = threadIdx.x >> 4;
    const int rowBase = blockIdx.y * 32;
    const int colBase = blockIdx.x * 32;

    #pragma unroll
    for (int r = 0; r < 4; ++r) {
        int idx = threadIdx.x + 256 * r;
        int row = idx >> 5;
        int c4 = (idx & 31) * 4;
        float4 va = *(const float4*)&X1[(rowBase + row) * DIM + c4];
        As[row][c4 + 0] = va.x; As[row][c4 + 1] = va.y;
        As[row][c4 + 2] = va.z; As[row][c4 + 3] = va.w;
        float4 vb = *(const float4*)&X2[(colBase + row) * DIM + c4];
        Bs[row][c4 + 0] = vb.x; Bs[row][c4 + 1] = vb.y;
        Bs[row][c4 + 2] = vb.z; Bs[row][c4 + 3] = vb.w;
    }
    __syncthreads();

    float acc[2][2] = {{0.f, 0.f}, {0.f, 0.f}};
    const int a0 = ty * 2, b0 = tx * 2;
    #pragma unroll 4
    for (int kk = 0; kk < DIM; ++kk) {
        float av0 = As[a0][kk], av1 = As[a0 + 1][kk];
        float bv0 = Bs[b0][kk], bv1 = Bs[b0 + 1][kk];
        acc[0][0] += av0 * bv0;
        acc[0][1] += av0 * bv1;
        acc[1][0] += av1 * bv0;
        acc[1][1] += av1 * bv1;
    }

    #pragma unroll
    for (int u = 0; u < 2; ++u)
        #pragma unroll
        for (int v = 0; v < 2; ++v) {
            int a = rowBase + a0 + u;
            int b = colBase + b0 + v;
            int d = a + b;
            int amin = (d > 2047) ? (d - 2047) : 0;
            Cd[diag_off(d) + (a - amin)] = K2f * (n1[a] + n2[b] - 2.0f * acc[u][v]);
        }
}

// ---------------- DP: 32 workgroups (1 wave each), global-memory pipeline ----
// WG b owns rows [64b+1, 64b+64]; lane l owns row 64b+l+1. At band-step s
// (1..2112) lane l computes cell (row, j=s-l). up via v_mov_dpp wave_shr:1
// (lane0 takes prev band's value from the inbox as DPP 'old'); diag = previous
// step's u; left = own r1. Interface: producer slot t = its step t+1's bottom-
// row value (col t-62); consumer step s reads slot s+62. flags[b] = chunks done.
#define DSTEP { int dd = d; \
                pu += (dd <= 2046) ? (dd + 1) : ((dd == 2047) ? 2047 : (4094 - dd)); \
                d = dd + 1; }
#define ISSUE8(B) { _Pragma("unroll") \
                    for (int k = 0; k < 8; ++k) { (B)[k] = pu[abase]; DSTEP } }

#define CHUNK_BODY(EDGE)                                                      \
  {                                                                           \
    const int s0 = JC * c;                                                    \
    const int abase = 64 * b + lane;                                          \
    int d = 64 * b + s0;                                                      \
    const float* pu = Cd + (diag_off(d) - ((d > 2047) ? (d - 2047) : 0));     \
    float bufr[3][8], rh[8];                                                  \
    ISSUE8(bufr[0]) ISSUE8(bufr[1])                                           \
    _Pragma("unroll")                                                         \
    for (int g = 0; g < 8; ++g) {                                             \
      if (g < 6) { ISSUE8(bufr[(g + 2) % 3]) }                                \
      const int sbase = s0 + 1 + g * 8;                                       \
      _Pragma("unroll")                                                       \
      for (int k = 0; k < 8; ++k) {                                           \
        float ringv = inbox[g * 8 + k];                                       \
        float u = __int_as_float(__builtin_amdgcn_update_dpp(                 \
                      __float_as_int(ringv), __float_as_int(r1),              \
                      0x138 /*wave_shr:1*/, 0xF, 0xF, false));                \
        float mn = fminf(fminf(u, r1), uprev);                                \
        float md = __builtin_amdgcn_fmed3f(u, r1, uprev);                     \
        float mx = fmaxf(fmaxf(u, r1), uprev);                                \
        float sm = mn - lg2(1.0f + ex2(mn - md) + ex2(mn - mx));              \
        float rn;                                                             \
        if (EDGE) rn = ((unsigned)(sbase + k - 1 - lane) <= 2047u)            \
                           ? (bufr[g % 3][k] + sm) : INFF;                    \
        else      rn = bufr[g % 3][k] + sm;                                   \
        rh[k] = rn;                                                           \
        uprev = u;                                                            \
        r1 = rn;                                                              \
      }                                                                       \
      if (!lastBand) {                                                        \
        if (l63) {                                                            \
          _Pragma("unroll")                                                   \
          for (int k = 0; k < 8; ++k) outst[g * 8 + k] = rh[k];               \
        }                                                                     \
      } else if (EDGE && sbase == 2105) {                                     \
        if (l63) out[0] = rh[6] * LN2f;   /* s=2111 -> R[2048][2048] */       \
      }                                                                       \
    }                                                                         \
  }

__global__ __launch_bounds__(64) void dp_kernel(const float* __restrict__ Cd,
                                                float* buf, int* flags,
                                                float* __restrict__ out) {
    __shared__ float inbox[JC];
    __shared__ float outst[JC];
    const int b = blockIdx.x;
    const int lane = threadIdx.x;
    const bool l63 = (lane == 63);
    const bool lastBand = (b == NBAND - 1);

    float* bufIn  = buf + (size_t)(b - 1) * SLOTS;   // valid for b>0
    float* bufOut = buf + (size_t)b * SLOTS;         // used for b<31

    float r1 = INFF;
    float uprev = (b == 0 && lane == 0) ? 0.0f : INFF;  // R[0][0]=0 feeds (1,1)

    for (int c = 0; c < NCHUNK; ++c) {
        // ---- acquire inbox (prev band cols for steps of this chunk) ----
        if (b > 0) {
            int need = c + 2; if (need > NCHUNK) need = NCHUNK;
            while (__hip_atomic_load(&flags[b - 1], __ATOMIC_ACQUIRE,
                                     __HIP_MEMORY_SCOPE_AGENT) < need)
                __builtin_amdgcn_s_sleep(2);
            inbox[lane] = __hip_atomic_load(&bufIn[JC * c + 63 + lane],
                                            __ATOMIC_RELAXED,
                                            __HIP_MEMORY_SCOPE_AGENT);
            __syncthreads();
        } else if (c == 0) {
            inbox[lane] = INFF;            // virtual row 0: R[0][j>=1] = inf
            __syncthreads();
        }

        if (c == 0 || c == NCHUNK - 1) { CHUNK_BODY(true) }
        else                           { CHUNK_BODY(false) }

        // ---- publish bottom row chunk + release flag ----
        if (!lastBand) {
            __syncthreads();
            float t = outst[lane];
            bufOut[JC * c + lane] = t;     // slot = producer step - 1
            __threadfence();
            if (lane == 0)
                __hip_atomic_store(&flags[b], c + 1, __ATOMIC_RELEASE,
                                   __HIP_MEMORY_SCOPE_AGENT);
        }
    }
}

extern "C" void kernel_launch(void* const* d_in, const int* in_sizes, int n_in,
                              void* d_out, int out_size, void* d_ws, size_t ws_size,
                              hipStream_t stream) {
    const float* x1 = (const float*)d_in[0];   // y
    const float* x2 = (const float*)d_in[1];   // x2
    float* out = (float*)d_out;

    float* Cd = (float*)d_ws;                  // 2048^2 floats
    float* n1 = Cd + M1 * M2;
    float* n2 = n1 + M1;
    float* buf = n2 + M2;                      // 31 * SLOTS floats (band interfaces)
    int* flags = (int*)(buf + (size_t)(NBAND - 1) * SLOTS);   // 32 ints

    norm_kernel<<<4096, 64, 0, stream>>>(x1, x2, n1, n2, flags);
    cost_kernel<<<dim3(M2 / 32, M1 / 32), 256, 0, stream>>>(x1, x2, n1, n2, Cd);
    dp_kernel<<<NBAND, 64, 0, stream>>>(Cd, buf, flags, out);
}

// Round 6
// 606.941 us; speedup vs baseline: 5.6696x; 1.0413x over previous
//
#include <hip/hip_runtime.h>
#include <hip/hip_bf16.h>

#define M1 2048
#define M2 2048
#define DIM 128
#define NBAND 32       // one 64-row band per workgroup (one wave)
#define JC 64          // steps per chunk
#define NCHUNK 33      // 2112 band-steps / 64
#define SLOTS 2176     // interface slots per band (2112 used + pad for c=32 reads)
#define INFF __builtin_inff()
#define K2f  1.4426950408889634f   // log2(e)
#define LN2f 0.6931471805599453f

// Fast transcendentals via raw VOP1 (avoids glibc __exp2f/__log2f macro clash).
__device__ __forceinline__ float ex2(float x) {
    float r; asm("v_exp_f32 %0, %1" : "=v"(r) : "v"(x)); return r;
}
__device__ __forceinline__ float lg2(float x) {
    float r; asm("v_log_f32 %0, %1" : "=v"(r) : "v"(x)); return r;
}

// Compact diagonal-major layout of the cost matrix:
// diag d holds cells (a, b=d-a) for a in [max(0,d-2047), min(2047,d)].
__device__ __host__ __forceinline__ int diag_off(int d) {
    if (d <= 2048) return d * (d + 1) / 2;
    int u = d - 2048;
    return 2098176 + u * 2047 - u * (u - 1) / 2;  // 2098176 = 2048*2049/2
}

// ---------------- row norms (+ flag init, runs before dp in stream order) ----
__global__ __launch_bounds__(64) void norm_kernel(const float* __restrict__ X1,
                                                  const float* __restrict__ X2,
                                                  float* __restrict__ n1,
                                                  float* __restrict__ n2,
                                                  int* __restrict__ flags) {
    if (blockIdx.x == 0 && threadIdx.x < NBAND) flags[threadIdx.x] = 0;
    int b = blockIdx.x;
    const float* src = (b < M1) ? X1 : X2;
    int row = b & (M1 - 1);
    int t = threadIdx.x;
    float a = src[row * DIM + t];
    float c = src[row * DIM + t + 64];
    float s = a * a + c * c;
    #pragma unroll
    for (int o = 32; o > 0; o >>= 1) s += __shfl_down(s, o);
    if (t == 0) ((b < M1) ? n1 : n2)[row] = s;
}

// ---------------- cost matrix (diag-major output, pre-scaled by log2 e) ----
__global__ __launch_bounds__(256) void cost_kernel(const float* __restrict__ X1,
                                                   const float* __restrict__ X2,
                                                   const float* __restrict__ n1,
                                                   const float* __restrict__ n2,
                                                   float* __restrict__ Cd) {
    __shared__ float As[32][129];
    __shared__ float Bs[32][129];
    const int tx = threadIdx.x & 15;
    const int ty = threadIdx.x >> 4;
    const int rowBase = blockIdx.y * 32;
    const int colBase = blockIdx.x * 32;

    #pragma unroll
    for (int r = 0; r < 4; ++r) {
        int idx = threadIdx.x + 256 * r;
        int row = idx >> 5;
        int c4 = (idx & 31) * 4;
        float4 va = *(const float4*)&X1[(rowBase + row) * DIM + c4];
        As[row][c4 + 0] = va.x; As[row][c4 + 1] = va.y;
        As[row][c4 + 2] = va.z; As[row][c4 + 3] = va.w;
        float4 vb = *(const float4*)&X2[(colBase + row) * DIM + c4];
        Bs[row][c4 + 0] = vb.x; Bs[row][c4 + 1] = vb.y;
        Bs[row][c4 + 2] = vb.z; Bs[row][c4 + 3] = vb.w;
    }
    __syncthreads();

    float acc[2][2] = {{0.f, 0.f}, {0.f, 0.f}};
    const int a0 = ty * 2, b0 = tx * 2;
    #pragma unroll 4
    for (int kk = 0; kk < DIM; ++kk) {
        float av0 = As[a0][kk], av1 = As[a0 + 1][kk];
        float bv0 = Bs[b0][kk], bv1 = Bs[b0 + 1][kk];
        acc[0][0] += av0 * bv0;
        acc[0][1] += av0 * bv1;
        acc[1][0] += av1 * bv0;
        acc[1][1] += av1 * bv1;
    }

    #pragma unroll
    for (int u = 0; u < 2; ++u)
        #pragma unroll
        for (int v = 0; v < 2; ++v) {
            int a = rowBase + a0 + u;
            int b = colBase + b0 + v;
            int d = a + b;
            int amin = (d > 2047) ? (d - 2047) : 0;
            Cd[diag_off(d) + (a - amin)] = K2f * (n1[a] + n2[b] - 2.0f * acc[u][v]);
        }
}

// ---------------- DP: 32 WGs (1 wave each), LDS-staged C, global pipeline ----
// WG b owns rows [64b+1, 64b+64]; lane l owns row 64b+l+1. At band-step s
// (1..2112) lane l computes cell (row, j=s-l). up via v_mov_dpp wave_shr:1
// (lane0 takes prev band's value from ib[] as DPP 'old'); diag = previous
// step's u; left = own r1. C chunks staged global->LDS one chunk ahead via
// global_load_lds (counted vmcnt(63): next chunk's loads stay in flight).
#define DSTEP { int dd = d; \
                pu += (dd <= 2046) ? (dd + 1) : ((dd == 2047) ? 2047 : (4094 - dd)); \
                d = dd + 1; }

#define CISSUE(cc, pb) { \
    int d = 64 * b + JC * (cc); \
    const float* pu = Cd + (diag_off(d) - ((d > 2047) ? (d - 2047) : 0)); \
    _Pragma("unroll") \
    for (int q = 0; q < JC; ++q) { \
        __builtin_amdgcn_global_load_lds( \
            (const __attribute__((address_space(1))) void*)(pu + abase), \
            (__attribute__((address_space(3))) void*)(&cbuf[pb][q][0]), 4, 0, 0); \
        DSTEP \
    } }

#define CHUNK_BODY(EDGE)                                                      \
  {                                                                           \
    const int s0 = JC * c;                                                    \
    float rc[2][8], rq[2][8], rh[8];                                          \
    _Pragma("unroll")                                                         \
    for (int k = 0; k < 8; ++k) {                                             \
        rc[0][k] = cbuf[cb][k][lane]; rq[0][k] = ib[cb][k];                   \
    }                                                                         \
    _Pragma("unroll")                                                         \
    for (int g = 0; g < 8; ++g) {                                             \
      const int cu = g & 1, nu = cu ^ 1;                                      \
      if (g < 7) {                                                            \
        _Pragma("unroll")                                                     \
        for (int k = 0; k < 8; ++k) {                                         \
          rc[nu][k] = cbuf[cb][(g + 1) * 8 + k][lane];                        \
          rq[nu][k] = ib[cb][(g + 1) * 8 + k];                                \
        }                                                                     \
      }                                                                       \
      const int sbase = s0 + 1 + g * 8;                                       \
      _Pragma("unroll")                                                       \
      for (int k = 0; k < 8; ++k) {                                           \
        float u = __int_as_float(__builtin_amdgcn_update_dpp(                 \
                      __float_as_int(rq[cu][k]), __float_as_int(r1),          \
                      0x138 /*wave_shr:1*/, 0xF, 0xF, false));                \
        float mn = fminf(fminf(u, r1), uprev);                                \
        float md = __builtin_amdgcn_fmed3f(u, r1, uprev);                     \
        float mx = fmaxf(fmaxf(u, r1), uprev);                                \
        float sm = mn - lg2(1.0f + ex2(mn - md) + ex2(mn - mx));              \
        float rn;                                                             \
        if (EDGE) rn = ((unsigned)(sbase + k - 1 - lane) <= 2047u)            \
                           ? (rc[cu][k] + sm) : INFF;                         \
        else      rn = rc[cu][k] + sm;                                        \
        rh[k] = rn;                                                           \
        uprev = u;                                                            \
        r1 = rn;                                                              \
      }                                                                       \
      if (!lastBand) {                                                        \
        if (l63) {                                                            \
          _Pragma("unroll")                                                   \
          for (int k = 0; k < 8; ++k) outst[g * 8 + k] = rh[k];               \
        }                                                                     \
      } else if (EDGE && sbase == 2105) {                                     \
        if (l63) out[0] = rh[6] * LN2f;   /* s=2111 -> R[2048][2048] */       \
      }                                                                       \
    }                                                                         \
  }

__global__ __launch_bounds__(64, 1) void dp_kernel(const float* __restrict__ Cd,
                                                   float* buf, int* flags,
                                                   float* __restrict__ out) {
    __shared__ float cbuf[2][JC][64];   // double-buffered C chunks
    __shared__ float ib[2][JC];         // inbox (prev band bottom-row values)
    __shared__ float outst[JC];
    const int b = blockIdx.x;
    const int lane = threadIdx.x;
    const bool l63 = (lane == 63);
    const bool lastBand = (b == NBAND - 1);
    const int abase = 64 * b + lane;

    float* bufIn  = buf + (size_t)(b - 1) * SLOTS;   // valid for b>0
    float* bufOut = buf + (size_t)b * SLOTS;         // used for b<31

    if (b == 0) { ib[0][lane] = INFF; ib[1][lane] = INFF; }  // virtual row 0

    float r1 = INFF;
    float uprev = (b == 0 && lane == 0) ? 0.0f : INFF;  // R[0][0]=0 feeds (1,1)

    CISSUE(0, 0)    // prefetch C chunk 0

    for (int c = 0; c < NCHUNK; ++c) {
        const int cb = c & 1, nb = cb ^ 1;

        // ---- acquire inbox (prev band cols for this chunk's steps) ----
        if (b > 0) {
            int need = c + 2; if (need > NCHUNK) need = NCHUNK;
            while (__hip_atomic_load(&flags[b - 1], __ATOMIC_ACQUIRE,
                                     __HIP_MEMORY_SCOPE_AGENT) < need)
                __builtin_amdgcn_s_sleep(1);
            __builtin_amdgcn_global_load_lds(
                (const __attribute__((address_space(1))) void*)(bufIn + JC * c + 63 + lane),
                (__attribute__((address_space(3))) void*)(&ib[cb][0]), 4, 0, 0);
        }

        // ---- issue next C chunk; wait for current (counted, non-draining) ----
        if (c + 1 < NCHUNK) {
            CISSUE(c + 1, nb)
            asm volatile("s_waitcnt vmcnt(63)" ::: "memory");
        } else {
            asm volatile("s_waitcnt vmcnt(0)" ::: "memory");
        }
        __builtin_amdgcn_sched_barrier(0);

        if (c == 0 || c == NCHUNK - 1) { CHUNK_BODY(true) }
        else                           { CHUNK_BODY(false) }

        // ---- publish bottom row chunk + release flag ----
        if (!lastBand) {
            __syncthreads();
            bufOut[JC * c + lane] = outst[lane];     // slot = producer step - 1
            if (lane == 0)
                __hip_atomic_store(&flags[b], c + 1, __ATOMIC_RELEASE,
                                   __HIP_MEMORY_SCOPE_AGENT);
        }
    }
}

extern "C" void kernel_launch(void* const* d_in, const int* in_sizes, int n_in,
                              void* d_out, int out_size, void* d_ws, size_t ws_size,
                              hipStream_t stream) {
    const float* x1 = (const float*)d_in[0];   // y
    const float* x2 = (const float*)d_in[1];   // x2
    float* out = (float*)d_out;

    float* Cd = (float*)d_ws;                  // 2048^2 floats
    float* n1 = Cd + M1 * M2;
    float* n2 = n1 + M1;
    float* buf = n2 + M2;                      // 31 * SLOTS floats (band interfaces)
    int* flags = (int*)(buf + (size_t)(NBAND - 1) * SLOTS);   // 32 ints

    norm_kernel<<<4096, 64, 0, stream>>>(x1, x2, n1, n2, flags);
    cost_kernel<<<dim3(M2 / 32, M1 / 32), 256, 0, stream>>>(x1, x2, n1, n2, Cd);
    dp_kernel<<<NBAND, 64, 0, stream>>>(Cd, buf, flags, out);
}

// Round 7
// 452.159 us; speedup vs baseline: 7.6104x; 1.3423x over previous
//
#include <hip/hip_runtime.h>
#include <hip/hip_bf16.h>

#define M1 2048
#define M2 2048
#define DIM 128
#define NBAND 32       // one 64-row band per workgroup (one wave)
#define NG 264         // 8-step groups per band (2112 steps)
#define INFF __builtin_inff()
#define K2f  1.4426950408889634f   // log2(e)
#define LN2f 0.6931471805599453f
#define SENT (-1)      // 0xFFFFFFFF sentinel (hipMemsetAsync 0xFF); never a finite float

// Fast transcendentals via raw VOP1 (avoids glibc __exp2f/__log2f macro clash).
__device__ __forceinline__ float ex2(float x) {
    float r; asm("v_exp_f32 %0, %1" : "=v"(r) : "v"(x)); return r;
}
__device__ __forceinline__ float lg2(float x) {
    float r; asm("v_log_f32 %0, %1" : "=v"(r) : "v"(x)); return r;
}

__device__ __forceinline__ int aload(const int* p) {
    return __hip_atomic_load(p, __ATOMIC_RELAXED, __HIP_MEMORY_SCOPE_AGENT);
}
__device__ __forceinline__ void astore(int* p, int v) {
    __hip_atomic_store(p, v, __ATOMIC_RELAXED, __HIP_MEMORY_SCOPE_AGENT);
}

// Compact diagonal-major layout of the cost matrix:
// diag d holds cells (a, b=d-a) for a in [max(0,d-2047), min(2047,d)].
__device__ __host__ __forceinline__ int diag_off(int d) {
    if (d <= 2048) return d * (d + 1) / 2;
    int u = d - 2048;
    return 2098176 + u * 2047 - u * (u - 1) / 2;  // 2098176 = 2048*2049/2
}

// ---------------- row norms ----------------
__global__ __launch_bounds__(64) void norm_kernel(const float* __restrict__ X1,
                                                  const float* __restrict__ X2,
                                                  float* __restrict__ n1,
                                                  float* __restrict__ n2) {
    int b = blockIdx.x;
    const float* src = (b < M1) ? X1 : X2;
    int row = b & (M1 - 1);
    int t = threadIdx.x;
    float a = src[row * DIM + t];
    float c = src[row * DIM + t + 64];
    float s = a * a + c * c;
    #pragma unroll
    for (int o = 32; o > 0; o >>= 1) s += __shfl_down(s, o);
    if (t == 0) ((b < M1) ? n1 : n2)[row] = s;
}

// ---------------- cost matrix (diag-major output, pre-scaled by log2 e) ----
__global__ __launch_bounds__(256) void cost_kernel(const float* __restrict__ X1,
                                                   const float* __restrict__ X2,
                                                   const float* __restrict__ n1,
                                                   const float* __restrict__ n2,
                                                   float* __restrict__ Cd) {
    __shared__ float As[32][129];
    __shared__ float Bs[32][129];
    const int tx = threadIdx.x & 15;
    const int ty = threadIdx.x >> 4;
    const int rowBase = blockIdx.y * 32;
    const int colBase = blockIdx.x * 32;

    #pragma unroll
    for (int r = 0; r < 4; ++r) {
        int idx = threadIdx.x + 256 * r;
        int row = idx >> 5;
        int c4 = (idx & 31) * 4;
        float4 va = *(const float4*)&X1[(rowBase + row) * DIM + c4];
        As[row][c4 + 0] = va.x; As[row][c4 + 1] = va.y;
        As[row][c4 + 2] = va.z; As[row][c4 + 3] = va.w;
        float4 vb = *(const float4*)&X2[(colBase + row) * DIM + c4];
        Bs[row][c4 + 0] = vb.x; Bs[row][c4 + 1] = vb.y;
        Bs[row][c4 + 2] = vb.z; Bs[row][c4 + 3] = vb.w;
    }
    __syncthreads();

    float acc[2][2] = {{0.f, 0.f}, {0.f, 0.f}};
    const int a0 = ty * 2, b0 = tx * 2;
    #pragma unroll 4
    for (int kk = 0; kk < DIM; ++kk) {
        float av0 = As[a0][kk], av1 = As[a0 + 1][kk];
        float bv0 = Bs[b0][kk], bv1 = Bs[b0 + 1][kk];
        acc[0][0] += av0 * bv0;
        acc[0][1] += av0 * bv1;
        acc[1][0] += av1 * bv0;
        acc[1][1] += av1 * bv1;
    }

    #pragma unroll
    for (int u = 0; u < 2; ++u)
        #pragma unroll
        for (int v = 0; v < 2; ++v) {
            int a = rowBase + a0 + u;
            int b = colBase + b0 + v;
            int d = a + b;
            int amin = (d > 2047) ? (d - 2047) : 0;
            Cd[diag_off(d) + (a - amin)] = K2f * (n1[a] + n2[b] - 2.0f * acc[u][v]);
        }
}

// ---------------- DP: 32 WGs (1 wave), sentinel-flow pipeline ----------------
// WG b owns rows [64b+1, 64b+64]; lane l owns row 64b+l+1. At band-step
// s = 8G+1+k lane l computes cell (row, j=s-l). up via v_mov_dpp wave_shr:1
// (lane0 takes prev band's col value as DPP 'old'); diag = previous step's u;
// left = own r1. Interface buf[b][j-1] (sentinel-initialized): producer lane63
// publishes col j = s-63 with a relaxed agent store; consumer validates its
// 8-word group (prefetched 2 groups = 16 steps ahead) and spins only on
// sentinel. No flags, no fences, no barriers.
#define DSTEP { int dd = d; \
    pu += (dd <= 2046) ? (dd + 1) : ((dd == 2047) ? 2047 : (4094 - dd)); \
    d = dd + 1; }

#define PREF_C(pb2) { _Pragma("unroll") \
    for (int k = 0; k < 8; ++k) { cld[pb2][k] = pu[abase]; DSTEP } }

#define PREF_I(Gp, pb2) { _Pragma("unroll") \
    for (int k = 0; k < 8; ++k) ibx[pb2][k] = aload(bin + 8 * (Gp) + k); }

#define VALID(Gv, pb2) { \
    int bad = 0; \
    _Pragma("unroll") for (int k = 0; k < 8; ++k) bad |= (ibx[pb2][k] == SENT); \
    while (__builtin_expect(bad != 0, 0)) { \
        __builtin_amdgcn_s_sleep(1); \
        bad = 0; \
        _Pragma("unroll") for (int k = 0; k < 8; ++k) { \
            ibx[pb2][k] = aload(bin + 8 * (Gv) + k); \
            bad |= (ibx[pb2][k] == SENT); } } }

#define COMPUTE(Gv, pb2, USEIB, VPRED) { \
    _Pragma("unroll") for (int k = 0; k < 8; ++k) { \
        float qv = (USEIB) ? __int_as_float(ibx[pb2][k]) : INFF; \
        float u = __int_as_float(__builtin_amdgcn_update_dpp( \
                      __float_as_int(qv), __float_as_int(r1), \
                      0x138 /*wave_shr:1*/, 0xF, 0xF, false)); \
        float mn = fminf(fminf(u, r1), uprev); \
        float md = __builtin_amdgcn_fmed3f(u, r1, uprev); \
        float mx = fmaxf(fmaxf(u, r1), uprev); \
        float sm = mn - lg2(1.0f + ex2(mn - md) + ex2(mn - mx)); \
        float rn; \
        if (VPRED) rn = ((unsigned)(8 * (Gv) + k - lane) <= 2047u) \
                            ? (cld[pb2][k] + sm) : INFF; \
        else       rn = cld[pb2][k] + sm; \
        rh[k] = rn; uprev = u; r1 = rn; } }

#define PUBLISH(Gv, PG) { if (l63) { _Pragma("unroll") \
    for (int k = 0; k < 8; ++k) { \
        int slot = 8 * (Gv) + k - 63; \
        if (!(PG) || (unsigned)slot < 2048u) \
            astore(bout + slot, __float_as_int(rh[k])); } } }

template<bool FIRST, bool LAST>
__device__ void dp_run(int band, int lane, const float* __restrict__ Cd,
                       const int* bin, int* bout, float* __restrict__ out) {
    const bool l63 = (lane == 63);
    const int abase = 64 * band + lane;
    int d = 64 * band;
    const float* pu = Cd + diag_off(d);      // amin(d)=0 since d<=1984
    float cld[4][8], rh[8];
    int ibx[4][8];
    float r1 = INFF;
    float uprev = (FIRST && lane == 0) ? 0.0f : INFF;   // R[0][0]=0 feeds (1,1)

    PREF_C(0) PREF_C(1)
    if (!FIRST) { PREF_I(0, 0) PREF_I(1, 1) }

    #pragma unroll
    for (int G = 0; G < 8; ++G) {            // HEAD: j>=1 predicate, guarded publish
        PREF_C((G + 2) & 3)
        if (!FIRST) { PREF_I(G + 2, (G + 2) & 3) VALID(G, G & 3) }
        COMPUTE(G, G & 3, !FIRST, true)
        if (!LAST) PUBLISH(G, true)
    }
    for (int G0 = 8; G0 < 252; G0 += 4) {    // STEADY: no guards at all
        #pragma unroll
        for (int gg = 0; gg < 4; ++gg) {
            const int G = G0 + gg;
            PREF_C((gg + 2) & 3)
            if (!FIRST) { PREF_I(G + 2, (gg + 2) & 3) VALID(G, gg) }
            COMPUTE(G, gg, !FIRST, false)
            if (!LAST) PUBLISH(G, false)
        }
    }
    #pragma unroll
    for (int G = 252; G < 256; ++G) {        // inbox prefetch runs out at G=255
        PREF_C((G + 2) & 3)
        if (!FIRST) {
            if (G + 2 < 256) PREF_I(G + 2, (G + 2) & 3)
            VALID(G, G & 3)
        }
        COMPUTE(G, G & 3, !FIRST, false)
        if (!LAST) PUBLISH(G, false)
    }
    #pragma unroll
    for (int G = 256; G < NG; ++G) {         // TAIL: cols>2048 invalid; no inbox
        if (G + 2 < NG) PREF_C((G + 2) & 3)
        COMPUTE(G, G & 3, false, true)
        if (!LAST) PUBLISH(G, (G == NG - 1))
        if (LAST && G == NG - 1 && l63) out[0] = rh[6] * LN2f;  // s=2111 -> R[2048][2048]
    }
}

__global__ __launch_bounds__(64, 1) void dp_kernel(const float* __restrict__ Cd,
                                                   int* buf, float* __restrict__ out) {
    const int b = blockIdx.x;
    const int lane = threadIdx.x;
    const int* bin = buf + (b - 1) * 2048;   // not dereferenced for b==0
    int* bout = buf + b * 2048;              // not stored for b==NBAND-1
    if (b == 0)                 dp_run<true,  false>(b, lane, Cd, bin, bout, out);
    else if (b == NBAND - 1)    dp_run<false, true >(b, lane, Cd, bin, bout, out);
    else                        dp_run<false, false>(b, lane, Cd, bin, bout, out);
}

extern "C" void kernel_launch(void* const* d_in, const int* in_sizes, int n_in,
                              void* d_out, int out_size, void* d_ws, size_t ws_size,
                              hipStream_t stream) {
    const float* x1 = (const float*)d_in[0];   // y
    const float* x2 = (const float*)d_in[1];   // x2
    float* out = (float*)d_out;

    float* Cd = (float*)d_ws;                  // 2048^2 floats
    float* n1 = Cd + M1 * M2;
    float* n2 = n1 + M1;
    int* buf = (int*)(n2 + M2);                // 31 * 2048 interface words

    hipMemsetAsync(buf, 0xFF, (size_t)(NBAND - 1) * 2048 * sizeof(int), stream);
    norm_kernel<<<4096, 64, 0, stream>>>(x1, x2, n1, n2);
    cost_kernel<<<dim3(M2 / 32, M1 / 32), 256, 0, stream>>>(x1, x2, n1, n2, Cd);
    dp_kernel<<<NBAND, 64, 0, stream>>>(Cd, buf, out);
}